// Round 11
// baseline (285.968 us; speedup 1.0000x reference)
//
#include <hip/hip_runtime.h>
#include <hip/hip_fp16.h>
#include <stdint.h>
#include <math.h>

#define BS    2
#define RAYS  514
#define NS    64
#define LSEQ  512
#define NF    257
#define HIDN  64
#define SPLIT 4
#define JC    16      // hidden columns per k2 block
#define K2REP 10      // DIAGNOSTIC: amplify k2 so it beats the ~42us fills in top-5

#define TWO_PI_F 6.28318530717958647692f

__device__ __forceinline__ uint32_t rotl32(uint32_t x, int d){ return (x<<d)|(x>>(32-d)); }

__device__ __forceinline__ void tf_rounds4(uint32_t& x0, uint32_t& x1, int a, int b, int c, int d){
  x0+=x1; x1=rotl32(x1,a); x1^=x0;
  x0+=x1; x1=rotl32(x1,b); x1^=x0;
  x0+=x1; x1=rotl32(x1,c); x1^=x0;
  x0+=x1; x1=rotl32(x1,d); x1^=x0;
}

// Threefry-2x32, 20 rounds, matching jax._src.prng.threefry2x32
__device__ void threefry2x32(uint32_t k0, uint32_t k1, uint32_t x0, uint32_t x1,
                             uint32_t& o0, uint32_t& o1)
{
  const uint32_t ks2 = k0 ^ k1 ^ 0x1BD11BDAu;
  x0 += k0; x1 += k1;
  tf_rounds4(x0,x1,13,15,26,6);   x0+=k1;  x1+=ks2+1u;
  tf_rounds4(x0,x1,17,29,16,24);  x0+=ks2; x1+=k0+2u;
  tf_rounds4(x0,x1,13,15,26,6);   x0+=k0;  x1+=k1+3u;
  tf_rounds4(x0,x1,17,29,16,24);  x0+=k1;  x1+=ks2+4u;
  tf_rounds4(x0,x1,13,15,26,6);   x0+=ks2; x1+=k0+5u;
  o0 = x0; o1 = x1;
}

// Reproduces _ray_directions() for ray r (verified round 0).
__device__ void ray_dir(int r, float d[3])
{
  if (r >= 512) { d[0]=0.f; d[1]=0.f; d[2] = (r==512) ? 1.0f : -1.0f; return; }
  int i = r >> 4, j = r & 15;
  uint32_t o0, o1;
  threefry2x32(0u, 42u, 0u, (uint32_t)i, o0, o1);
  uint32_t bits = o0 ^ o1;
  float u = __uint_as_float((bits >> 9) | 0x3F800000u) - 1.0f;   // uniform [0,1)
  const float step = TWO_PI_F / 32.0f;
  float a = (float)i * step + step * u;
  float e = acosf(2.0f * ((float)(j+1) * (1.0f/17.0f)) - 1.0f);
  float se = sinf(e);
  d[0] = cosf(a) * se;
  d[1] = sinf(a) * se;
  d[2] = cosf(e);
}

__device__ __forceinline__ float dval(int s){ return ((float)s*(1.0f/63.0f))*7.9f + 0.1f; }

__device__ __forceinline__ uint32_t pk2(float a, float b){
  return (uint32_t)__half_as_ushort(__float2half(a)) |
         ((uint32_t)__half_as_ushort(__float2half(b)) << 16);
}

// K1: unchanged from round 10 (byte-identical behavior).
__global__ __launch_bounds__(256)
void k1_rays(const float* __restrict__ rays_o, const float* __restrict__ position_tx,
             const float* __restrict__ W1, const float* __restrict__ b1,
             const float* __restrict__ w_attn,
             __half* __restrict__ wh, float* __restrict__ w_arr, int* __restrict__ delay_arr,
             float* __restrict__ g, float* __restrict__ out)
{
  const int tid = threadIdx.x;
  const int wid = tid >> 6, lane = tid & 63;       // lane = s index
  const int br = blockIdx.x*4 + wid;               // 257*4 = 1028 = BS*RAYS
  const int b = br / RAYS, r = br % RAYS;

  { // zero the atomic accumulators (65792 threads cover g:65536 and out:1028)
    int gi = blockIdx.x*256 + tid;
    if (gi < BS*NS*LSEQ) g[gi] = 0.f;
    if (gi < BS*NF*2) out[gi] = 0.f;
  }

  float dir[3]; ray_dir(r, dir);
  const float mn[3] = {-5.f,-5.f,-3.f}, mx[3] = {5.f,5.f,3.f};
  float ro[3], ntx[3];
  #pragma unroll
  for (int c=0;c<3;c++){
    ro[c] = rays_o[b*3+c];
    float t = position_tx[b*3+c];
    ntx[c] = 2.0f*(t - mn[c])/(mx[c]-mn[c]) - 1.0f;
  }

  const float dv = dval(lane);
  float feat[9], dd2 = 0.f;
  #pragma unroll
  for (int c=0;c<3;c++){
    float pt = ro[c] + dir[c]*dv;
    float npt = 2.0f*(pt - mn[c])/(mx[c]-mn[c]) - 1.0f;
    float ddc = ((ntx[c]-npt) + 1.0f)/2.0f*(mx[c]-mn[c]) + mn[c];
    dd2 += ddc*ddc;
    feat[c]   = npt;
    feat[3+c] = -dir[c];
    feat[6+c] = ntx[c];
  }

  float h[HIDN];
  float av = 0.f;
  #pragma unroll
  for (int j=0; j<HIDN; j++){
    float hj = b1[j];
    #pragma unroll
    for (int f=0; f<9; f++) hj = fmaf(feat[f], W1[f*HIDN + j], hj);
    hj = fmaxf(hj, 0.0f);
    h[j] = hj;
    av = fmaf(hj, w_attn[j], av);
  }

  float attn = fmaxf(av, 0.f) + log1pf(expf(-fabsf(av)));   // softplus
  float dist = (lane < NS-1) ? (dval(lane+1) - dv) : 1e10f;
  float alpha = 1.0f - expf(-attn*dist);

  // inclusive multiplicative scan of (1-alpha+1e-6), shifted -> transmittance
  float fac = 1.0f - alpha + 1e-6f;
  float scan = fac;
  #pragma unroll
  for (int m=1; m<64; m<<=1){
    float up = __shfl_up(scan, m, 64);
    if (lane >= m) scan *= up;
  }
  float T = __shfl_up(scan, 1, 64);
  if (lane == 0) T = 1.0f;
  float wgt = T * alpha;

  float delf = fminf(fmaxf(rintf(sqrtf(dd2)*16000.0f/343.0f), 0.f), 511.f);

  const int bsid = b*NS + lane;
  const int o2 = bsid*RAYS + r;
  w_arr[o2] = wgt;
  delay_arr[o2] = (int)delf;

  // quartered store: quarter p -> [p][bsid][r][16] halves (32 B per quarter)
  #pragma unroll
  for (int p=0; p<SPLIT; p++){
    uint4 v0, v1;
    v0.x = pk2(wgt*h[p*16+ 0], wgt*h[p*16+ 1]);
    v0.y = pk2(wgt*h[p*16+ 2], wgt*h[p*16+ 3]);
    v0.z = pk2(wgt*h[p*16+ 4], wgt*h[p*16+ 5]);
    v0.w = pk2(wgt*h[p*16+ 6], wgt*h[p*16+ 7]);
    v1.x = pk2(wgt*h[p*16+ 8], wgt*h[p*16+ 9]);
    v1.y = pk2(wgt*h[p*16+10], wgt*h[p*16+11]);
    v1.z = pk2(wgt*h[p*16+12], wgt*h[p*16+13]);
    v1.w = pk2(wgt*h[p*16+14], wgt*h[p*16+15]);
    uint4* dst = (uint4*)(wh + (((size_t)p*BS*NS + bsid)*RAYS + r)*16);
    dst[0] = v0; dst[1] = v1;
  }
}

// K2: round-10 body, DIAGNOSTICALLY replicated K2REP x. Replica `rep` does
// byte-identical work but atomicAdds into its own g replica (same 4-block
// contention per address as the real one). rep 0 = the real computation.
__global__ __launch_bounds__(512)
void k2_bucket(const __half* __restrict__ wh, const float* __restrict__ w_arr,
               const int* __restrict__ delay_arr,
               const float* __restrict__ W_sig, const float* __restrict__ b_sig,
               float* __restrict__ g)
{
  __shared__ float bucket[LSEQ][JC+1];   // col 16 = w column; 34,816 B
  __shared__ float part[32][JC+1];       // 2,176 B
  __shared__ int   delay_l[RAYS];        // 2,056 B
  __shared__ float w_l[RAYS];            // 2,056 B  (total ~41 KB)
  const int rep = blockIdx.x >> 9;               // replica id (0 = real)
  const int blk = blockIdx.x & 511;
  float* __restrict__ gt = g + (size_t)rep * (BS*NS*LSEQ);
  const int bsid = blk / SPLIT, p = blk % SPLIT;
  const int tid = threadIdx.x;
  const int obase = bsid * RAYS;

  for (int i = tid; i < LSEQ*(JC+1); i += 512) (&bucket[0][0])[i] = 0.f;
  for (int i = tid; i < RAYS; i += 512){
    delay_l[i] = delay_arr[obase + i];
    if (p == 0) w_l[i] = w_arr[obase + i];
  }
  __syncthreads();

  // scatter: 1028 uint4s (2 per ray), 3 coalesced sweeps; 8 LDS atomics each
  {
    const uint4* whp = (const uint4*)(wh + ((size_t)p*BS*NS + bsid)*RAYS*16);
    #pragma unroll
    for (int i=0; i<3; i++){
      int idx = i*512 + tid;
      if (idx < RAYS*2){
        int r = idx >> 1, c8 = (idx & 1) << 3;
        uint4 v = whp[idx];
        int d = delay_l[r];
        float* brow = &bucket[d][c8];
        atomicAdd(&brow[0], __half2float(__ushort_as_half((ushort)(v.x & 0xFFFF))));
        atomicAdd(&brow[1], __half2float(__ushort_as_half((ushort)(v.x >> 16))));
        atomicAdd(&brow[2], __half2float(__ushort_as_half((ushort)(v.y & 0xFFFF))));
        atomicAdd(&brow[3], __half2float(__ushort_as_half((ushort)(v.y >> 16))));
        atomicAdd(&brow[4], __half2float(__ushort_as_half((ushort)(v.z & 0xFFFF))));
        atomicAdd(&brow[5], __half2float(__ushort_as_half((ushort)(v.z >> 16))));
        atomicAdd(&brow[6], __half2float(__ushort_as_half((ushort)(v.w & 0xFFFF))));
        atomicAdd(&brow[7], __half2float(__ushort_as_half((ushort)(v.w >> 16))));
        if (p == 0 && c8 == 0) atomicAdd(&bucket[d][JC], w_l[r]);
      }
    }
  }
  __syncthreads();

  // blocked inclusive scan: 32 segs x 16 rows (w col scanned by col==15, p==0)
  const int seg = tid >> 4, col = tid & 15, d0 = seg*16;
  {
    float run = 0.f;
    for (int k=0;k<16;k++){ run += bucket[d0+k][col]; bucket[d0+k][col] = run; }
    part[seg][col] = run;
    if (p == 0 && col == 15){
      float rw = 0.f;
      for (int k=0;k<16;k++){ rw += bucket[d0+k][JC]; bucket[d0+k][JC] = rw; }
      part[seg][JC] = rw;
    }
  }
  __syncthreads();
  {
    float off = 0.f;
    for (int t=0;t<seg;t++) off += part[t][col];
    for (int k=0;k<16;k++) bucket[d0+k][col] += off;
    if (p == 0 && col == 15){
      float ow = 0.f;
      for (int t=0;t<seg;t++) ow += part[t][JC];
      for (int k=0;k<16;k++) bucket[d0+k][JC] += ow;
    }
  }
  __syncthreads();

  // dot + mask + path loss -> atomicAdd into gt[bsid][l]  (one l per thread)
  const int s = bsid % NS;
  const float dv = dval(s);
  const float shiftf = rintf((16000.0f*dv)/343.0f);
  const int shift = (int)shiftf;
  const int jbase = p*JC;
  {
    const int l = tid;
    float mt = (((float)(LSEQ-1-l)) - shiftf > 0.f) ? 1.f : 0.f;
    if (mt > 0.f){
      float acc = 0.f;
      #pragma unroll
      for (int jj=0;jj<JC;jj++) acc += bucket[l][jj] * W_sig[(jbase+jj)*LSEQ + l];
      if (p == 0) acc += b_sig[l] * bucket[l][JC];
      int pli = shift + l;
      if (pli < 4) pli = 5;                     // path_loss[:4] = path_loss[5]
      float ideal = ((float)pli/16000.0f)*343.0f;
      atomicAdd(&gt[bsid*LSEQ + l], acc / (ideal + 0.001f));
    }
  }
}

// K3: unchanged from round 10.
__global__ __launch_bounds__(256)
void k3_dft(const float* __restrict__ g, float* __restrict__ out)
{
  __shared__ float4 gs4[LSEQ/4];
  __shared__ float red[4][64][2];
  const int blk = blockIdx.x;
  const int bsid = blk >> 2, grp = blk & 3;
  const int b = bsid / NS, s = bsid % NS;
  const int tid = threadIdx.x;
  const int c = tid >> 6, bl = tid & 63;         // c = l-chunk wave, bl = bin

  if (tid < LSEQ/4) gs4[tid] = ((const float4*)(g + bsid*LSEQ))[tid];
  __syncthreads();

  const int k = grp*64 + bl;
  float re = 0.f, im = 0.f;
  {
    float s1, c1; sincosf(-(TWO_PI_F/512.0f)*(float)k, &s1, &c1);
    float c2 = c1*c1 - s1*s1,  s2 = 2.0f*c1*s1;
    float c3 = c1*c2 - s1*s2,  s3 = c1*s2 + s1*c2;
    float c4 = c2*c2 - s2*s2,  s4 = 2.0f*c2*s2;
    const int l0 = c*128;
    int t0 = (k*l0) & (LSEQ-1);
    float wi, wr; sincosf(-(TWO_PI_F/512.0f)*(float)t0, &wi, &wr);
    for (int q=0; q<32; q++){
      float4 gv = gs4[c*32 + q];                 // wave-uniform broadcast
      float pr = gv.x + gv.y*c1 + gv.z*c2 + gv.w*c3;
      float pi =        gv.y*s1 + gv.z*s2 + gv.w*s3;
      re = fmaf(pr, wr, re); re = fmaf(-pi, wi, re);
      im = fmaf(pr, wi, im); im = fmaf( pi, wr, im);
      float nr = wr*c4 - wi*s4;
      wi = fmaf(wr, s4, wi*c4);
      wr = nr;
    }
  }
  red[c][bl][0] = re; red[c][bl][1] = im;
  __syncthreads();

  const float cfrac = (16000.0f*dval(s))/343.0f; // fractional pts2rx_idx
  if (tid < 64){
    const int kk = grp*64 + tid;
    float rs = red[0][tid][0] + red[1][tid][0] + red[2][tid][0] + red[3][tid][0];
    float is = red[0][tid][1] + red[1][tid][1] + red[2][tid][1] + red[3][tid][1];
    float ang = -(TWO_PI_F/512.0f)*((float)kk*cfrac);
    float sp, cp; sincosf(ang, &sp, &cp);
    atomicAdd(&out[(b*NF + kk)*2],     rs*cp - is*sp);
    atomicAdd(&out[(b*NF + kk)*2 + 1], rs*sp + is*cp);
  } else if (grp == 0 && tid < 128){
    int t = tid - 64;
    float4 a = gs4[t], bq = gs4[t+64];
    float alt = (a.x - a.y + a.z - a.w) + (bq.x - bq.y + bq.z - bq.w);
    #pragma unroll
    for (int m=32; m>=1; m>>=1) alt += __shfl_xor(alt, m, 64);
    if (t == 0){
      float ang = -(TWO_PI_F/512.0f)*(256.0f*cfrac);
      float sp, cp; sincosf(ang, &sp, &cp);
      atomicAdd(&out[(b*NF + 256)*2],     alt*cp);
      atomicAdd(&out[(b*NF + 256)*2 + 1], alt*sp);
    }
  }
}

extern "C" void kernel_launch(void* const* d_in, const int* in_sizes, int n_in,
                              void* d_out, int out_size, void* d_ws, size_t ws_size,
                              hipStream_t stream)
{
  const float* rays_o      = (const float*)d_in[0];
  const float* position_tx = (const float*)d_in[1];
  const float* W1          = (const float*)d_in[2];
  const float* b1          = (const float*)d_in[3];
  const float* w_attn      = (const float*)d_in[4];
  const float* W_sig       = (const float*)d_in[5];
  const float* b_sig       = (const float*)d_in[6];
  float* out = (float*)d_out;

  // workspace layout (~11.5 MB total)
  char* ws = (char*)d_ws;
  __half* wh       = (__half*)ws;                               // 4*128*514*16*2B = 8,421,376
  float* w_arr     = (float*)(ws + 8421376);                    // 263,168
  int*   delay_arr = (int*)  (ws + 8421376 + 263168);           // 263,168
  float* g         = (float*)(ws + 8421376 + 2*263168);         // K2REP * 262,144
  // g replica 0 = real; replicas 1..K2REP-1 are diagnostic dummies

  k1_rays  <<<(BS*RAYS)/4,       256, 0, stream>>>(rays_o, position_tx, W1, b1, w_attn,
                                                   wh, w_arr, delay_arr, g, out);
  k2_bucket<<<BS*NS*SPLIT*K2REP, 512, 0, stream>>>(wh, w_arr, delay_arr, W_sig, b_sig, g);
  k3_dft   <<<BS*NS*4,           256, 0, stream>>>(g, out);
}

// Round 12
// 56.771 us; speedup vs baseline: 5.0372x; 5.0372x over previous
//
#include <hip/hip_runtime.h>
#include <hip/hip_fp16.h>
#include <stdint.h>
#include <math.h>

#define BS    2
#define RAYS  514
#define NS    64
#define LSEQ  512
#define NF    257
#define HIDN  64
#define SPLIT 4
#define JC    16      // hidden columns per k2 block

#define TWO_PI_F 6.28318530717958647692f

__device__ __forceinline__ uint32_t rotl32(uint32_t x, int d){ return (x<<d)|(x>>(32-d)); }

__device__ __forceinline__ void tf_rounds4(uint32_t& x0, uint32_t& x1, int a, int b, int c, int d){
  x0+=x1; x1=rotl32(x1,a); x1^=x0;
  x0+=x1; x1=rotl32(x1,b); x1^=x0;
  x0+=x1; x1=rotl32(x1,c); x1^=x0;
  x0+=x1; x1=rotl32(x1,d); x1^=x0;
}

// Threefry-2x32, 20 rounds, matching jax._src.prng.threefry2x32
__device__ void threefry2x32(uint32_t k0, uint32_t k1, uint32_t x0, uint32_t x1,
                             uint32_t& o0, uint32_t& o1)
{
  const uint32_t ks2 = k0 ^ k1 ^ 0x1BD11BDAu;
  x0 += k0; x1 += k1;
  tf_rounds4(x0,x1,13,15,26,6);   x0+=k1;  x1+=ks2+1u;
  tf_rounds4(x0,x1,17,29,16,24);  x0+=ks2; x1+=k0+2u;
  tf_rounds4(x0,x1,13,15,26,6);   x0+=k0;  x1+=k1+3u;
  tf_rounds4(x0,x1,17,29,16,24);  x0+=k1;  x1+=ks2+4u;
  tf_rounds4(x0,x1,13,15,26,6);   x0+=ks2; x1+=k0+5u;
  o0 = x0; o1 = x1;
}

// Reproduces _ray_directions() for ray r (verified round 0).
__device__ void ray_dir(int r, float d[3])
{
  if (r >= 512) { d[0]=0.f; d[1]=0.f; d[2] = (r==512) ? 1.0f : -1.0f; return; }
  int i = r >> 4, j = r & 15;
  uint32_t o0, o1;
  threefry2x32(0u, 42u, 0u, (uint32_t)i, o0, o1);
  uint32_t bits = o0 ^ o1;
  float u = __uint_as_float((bits >> 9) | 0x3F800000u) - 1.0f;   // uniform [0,1)
  const float step = TWO_PI_F / 32.0f;
  float a = (float)i * step + step * u;
  float e = acosf(2.0f * ((float)(j+1) * (1.0f/17.0f)) - 1.0f);
  float se = sinf(e);
  d[0] = cosf(a) * se;
  d[1] = sinf(a) * se;
  d[2] = cosf(e);
}

__device__ __forceinline__ float dval(int s){ return ((float)s*(1.0f/63.0f))*7.9f + 0.1f; }

__device__ __forceinline__ uint32_t pk2(float a, float b){
  return (uint32_t)__half_as_ushort(__float2half(a)) |
         ((uint32_t)__half_as_ushort(__float2half(b)) << 16);
}

// K1 v2: 2 waves per (b,r); wave w computes hidden cols j in [w*32,(w+1)*32).
// av combined via one LDS exchange; both waves then compute the IDENTICAL
// transmittance scan (same per-lane fac), so no further broadcast is needed.
// Grid 1028 -> 2056 waves (2/SIMD vs 1 before).
__global__ __launch_bounds__(128)
void k1_rays(const float* __restrict__ rays_o, const float* __restrict__ position_tx,
             const float* __restrict__ W1, const float* __restrict__ b1,
             const float* __restrict__ w_attn,
             __half* __restrict__ wh, float* __restrict__ w_arr, int* __restrict__ delay_arr,
             float* __restrict__ g, float* __restrict__ out)
{
  __shared__ float avs[2][64];
  const int tid = threadIdx.x;
  const int wv = tid >> 6, lane = tid & 63;        // lane = s index
  const int br = blockIdx.x;                       // one (b,r) per block
  const int b = br / RAYS, r = br % RAYS;
  const int jbase = wv * 32;

  { // zero the atomic accumulators (1028*128 threads cover g:65536, out:1028)
    int gi = blockIdx.x*128 + tid;
    if (gi < BS*NS*LSEQ) g[gi] = 0.f;
    if (gi < BS*NF*2) out[gi] = 0.f;
  }

  float dir[3]; ray_dir(r, dir);
  const float mn[3] = {-5.f,-5.f,-3.f}, mx[3] = {5.f,5.f,3.f};
  float ro[3], ntx[3];
  #pragma unroll
  for (int c=0;c<3;c++){
    ro[c] = rays_o[b*3+c];
    float t = position_tx[b*3+c];
    ntx[c] = 2.0f*(t - mn[c])/(mx[c]-mn[c]) - 1.0f;
  }

  const float dv = dval(lane);
  float feat[9], dd2 = 0.f;
  #pragma unroll
  for (int c=0;c<3;c++){
    float pt = ro[c] + dir[c]*dv;
    float npt = 2.0f*(pt - mn[c])/(mx[c]-mn[c]) - 1.0f;
    float ddc = ((ntx[c]-npt) + 1.0f)/2.0f*(mx[c]-mn[c]) + mn[c];
    dd2 += ddc*ddc;
    feat[c]   = npt;
    feat[3+c] = -dir[c];
    feat[6+c] = ntx[c];
  }

  float h[32];
  float avp = 0.f;
  #pragma unroll
  for (int jj=0; jj<32; jj++){
    const int j = jbase + jj;
    float hj = b1[j];
    #pragma unroll
    for (int f=0; f<9; f++) hj = fmaf(feat[f], W1[f*HIDN + j], hj);
    hj = fmaxf(hj, 0.0f);
    h[jj] = hj;
    avp = fmaf(hj, w_attn[j], avp);
  }
  avs[wv][lane] = avp;
  __syncthreads();
  float av = avs[0][lane] + avs[1][lane];

  float attn = fmaxf(av, 0.f) + log1pf(expf(-fabsf(av)));   // softplus
  float dist = (lane < NS-1) ? (dval(lane+1) - dv) : 1e10f;
  float alpha = 1.0f - expf(-attn*dist);

  // inclusive multiplicative scan of (1-alpha+1e-6), shifted -> transmittance
  float fac = 1.0f - alpha + 1e-6f;
  float scan = fac;
  #pragma unroll
  for (int m=1; m<64; m<<=1){
    float up = __shfl_up(scan, m, 64);
    if (lane >= m) scan *= up;
  }
  float T = __shfl_up(scan, 1, 64);
  if (lane == 0) T = 1.0f;
  float wgt = T * alpha;

  const int bsid = b*NS + lane;
  const int o2 = bsid*RAYS + r;
  if (wv == 0){
    float delf = fminf(fmaxf(rintf(sqrtf(dd2)*16000.0f/343.0f), 0.f), 511.f);
    w_arr[o2] = wgt;
    delay_arr[o2] = (int)delf;
  }

  // each wave stores its two p-quarters: p = wv*2 + pp, cols h[pp*16..+15]
  #pragma unroll
  for (int pp=0; pp<2; pp++){
    const int p = wv*2 + pp;
    uint4 v0, v1;
    v0.x = pk2(wgt*h[pp*16+ 0], wgt*h[pp*16+ 1]);
    v0.y = pk2(wgt*h[pp*16+ 2], wgt*h[pp*16+ 3]);
    v0.z = pk2(wgt*h[pp*16+ 4], wgt*h[pp*16+ 5]);
    v0.w = pk2(wgt*h[pp*16+ 6], wgt*h[pp*16+ 7]);
    v1.x = pk2(wgt*h[pp*16+ 8], wgt*h[pp*16+ 9]);
    v1.y = pk2(wgt*h[pp*16+10], wgt*h[pp*16+11]);
    v1.z = pk2(wgt*h[pp*16+12], wgt*h[pp*16+13]);
    v1.w = pk2(wgt*h[pp*16+14], wgt*h[pp*16+15]);
    uint4* dst = (uint4*)(wh + (((size_t)p*BS*NS + bsid)*RAYS + r)*16);
    dst[0] = v0; dst[1] = v1;
  }
}

// K2 v3: 1024 threads (16 waves; with 2 blocks/CU -> 32 waves/CU, chip max).
// Scatter 1 sweep; scan = 8-row segments + wave-parallel shfl offset scan +
// 8-row add-back; dot split across thread halves (jj 0-7 / 8-15), each half
// atomicAdds its partial into g (linear => exact).
__global__ __launch_bounds__(1024, 8)
void k2_bucket(const __half* __restrict__ wh, const float* __restrict__ w_arr,
               const int* __restrict__ delay_arr,
               const float* __restrict__ W_sig, const float* __restrict__ b_sig,
               float* __restrict__ g)
{
  __shared__ float bucket[LSEQ][JC+1];   // col 16 = w column; 34,816 B
  __shared__ float part[64][JC+1];       // 4,352 B
  __shared__ int   delay_l[RAYS];        // 2,056 B
  __shared__ float w_l[RAYS];            // 2,056 B  (total ~43.3 KB -> 2 blocks/CU)
  const int blk = blockIdx.x;
  const int bsid = blk / SPLIT, p = blk % SPLIT;
  const int tid = threadIdx.x;
  const int obase = bsid * RAYS;

  for (int i = tid; i < LSEQ*(JC+1); i += 1024) (&bucket[0][0])[i] = 0.f;
  if (tid < RAYS){
    delay_l[tid] = delay_arr[obase + tid];
    if (p == 0) w_l[tid] = w_arr[obase + tid];
  }
  __syncthreads();

  // scatter: 1028 uint4s, one sweep (threads 0-3 take the 4 leftovers)
  {
    const uint4* whp = (const uint4*)(wh + ((size_t)p*BS*NS + bsid)*RAYS*16);
    for (int idx = tid; idx < RAYS*2; idx += 1024){
      int r = idx >> 1, c8 = (idx & 1) << 3;
      uint4 v = whp[idx];
      int d = delay_l[r];
      float* brow = &bucket[d][c8];
      atomicAdd(&brow[0], __half2float(__ushort_as_half((ushort)(v.x & 0xFFFF))));
      atomicAdd(&brow[1], __half2float(__ushort_as_half((ushort)(v.x >> 16))));
      atomicAdd(&brow[2], __half2float(__ushort_as_half((ushort)(v.y & 0xFFFF))));
      atomicAdd(&brow[3], __half2float(__ushort_as_half((ushort)(v.y >> 16))));
      atomicAdd(&brow[4], __half2float(__ushort_as_half((ushort)(v.z & 0xFFFF))));
      atomicAdd(&brow[5], __half2float(__ushort_as_half((ushort)(v.z >> 16))));
      atomicAdd(&brow[6], __half2float(__ushort_as_half((ushort)(v.w & 0xFFFF))));
      atomicAdd(&brow[7], __half2float(__ushort_as_half((ushort)(v.w >> 16))));
      if (p == 0 && c8 == 0) atomicAdd(&bucket[d][JC], w_l[r]);
    }
  }
  __syncthreads();

  // pass 1: 64 segs x 8 rows inclusive scan; seg totals -> part
  const int seg = tid >> 4, col = tid & 15, d0 = seg*8;
  {
    float run = 0.f;
    #pragma unroll
    for (int k=0;k<8;k++){ run += bucket[d0+k][col]; bucket[d0+k][col] = run; }
    part[seg][col] = run;
    if (p == 0 && col == 15){
      float rw = 0.f;
      #pragma unroll
      for (int k=0;k<8;k++){ rw += bucket[d0+k][JC]; bucket[d0+k][JC] = rw; }
      part[seg][JC] = rw;
    }
  }
  __syncthreads();

  // pass 2: wave w scans part[:][w] (64 segs) via shfl_up; wave 15 also w-col
  {
    const int w = tid >> 6, lam = tid & 63;
    float v = part[lam][w];
    #pragma unroll
    for (int m=1;m<64;m<<=1){ float u = __shfl_up(v, m, 64); if (lam >= m) v += u; }
    part[lam][w] = v;
    if (w == 15 && p == 0){
      float vw = part[lam][JC];
      #pragma unroll
      for (int m=1;m<64;m<<=1){ float u = __shfl_up(vw, m, 64); if (lam >= m) vw += u; }
      part[lam][JC] = vw;
    }
  }
  __syncthreads();

  // pass 3: add exclusive segment offsets back
  {
    float off = (seg > 0) ? part[seg-1][col] : 0.f;
    #pragma unroll
    for (int k=0;k<8;k++) bucket[d0+k][col] += off;
    if (p == 0 && col == 15){
      float ow = (seg > 0) ? part[seg-1][JC] : 0.f;
      #pragma unroll
      for (int k=0;k<8;k++) bucket[d0+k][JC] += ow;
    }
  }
  __syncthreads();

  // dot + mask + path loss, split across thread halves; atomicAdd into g
  const int s = bsid % NS;
  const float dv = dval(s);
  const float shiftf = rintf((16000.0f*dv)/343.0f);
  const int shift = (int)shiftf;
  const int jbase = p*JC;
  {
    const int half = tid >> 9, l = tid & 511;
    float mt = (((float)(LSEQ-1-l)) - shiftf > 0.f) ? 1.f : 0.f;
    if (mt > 0.f){
      float acc = 0.f;
      const int j0 = half*8;
      #pragma unroll
      for (int jj=0;jj<8;jj++) acc += bucket[l][j0+jj] * W_sig[(jbase+j0+jj)*LSEQ + l];
      if (p == 0 && half == 1) acc += b_sig[l] * bucket[l][JC];
      int pli = shift + l;
      if (pli < 4) pli = 5;                     // path_loss[:4] = path_loss[5]
      float ideal = ((float)pli/16000.0f)*343.0f;
      atomicAdd(&g[bsid*LSEQ + l], acc / (ideal + 0.001f));
    }
  }
}

// K3: unchanged from round 10 (cubic-factorized register-twiddle DFT).
__global__ __launch_bounds__(256)
void k3_dft(const float* __restrict__ g, float* __restrict__ out)
{
  __shared__ float4 gs4[LSEQ/4];
  __shared__ float red[4][64][2];
  const int blk = blockIdx.x;
  const int bsid = blk >> 2, grp = blk & 3;
  const int b = bsid / NS, s = bsid % NS;
  const int tid = threadIdx.x;
  const int c = tid >> 6, bl = tid & 63;         // c = l-chunk wave, bl = bin

  if (tid < LSEQ/4) gs4[tid] = ((const float4*)(g + bsid*LSEQ))[tid];
  __syncthreads();

  const int k = grp*64 + bl;
  float re = 0.f, im = 0.f;
  {
    float s1, c1; sincosf(-(TWO_PI_F/512.0f)*(float)k, &s1, &c1);
    float c2 = c1*c1 - s1*s1,  s2 = 2.0f*c1*s1;
    float c3 = c1*c2 - s1*s2,  s3 = c1*s2 + s1*c2;
    float c4 = c2*c2 - s2*s2,  s4 = 2.0f*c2*s2;
    const int l0 = c*128;
    int t0 = (k*l0) & (LSEQ-1);
    float wi, wr; sincosf(-(TWO_PI_F/512.0f)*(float)t0, &wi, &wr);
    for (int q=0; q<32; q++){
      float4 gv = gs4[c*32 + q];                 // wave-uniform broadcast
      float pr = gv.x + gv.y*c1 + gv.z*c2 + gv.w*c3;
      float pi =        gv.y*s1 + gv.z*s2 + gv.w*s3;
      re = fmaf(pr, wr, re); re = fmaf(-pi, wi, re);
      im = fmaf(pr, wi, im); im = fmaf( pi, wr, im);
      float nr = wr*c4 - wi*s4;
      wi = fmaf(wr, s4, wi*c4);
      wr = nr;
    }
  }
  red[c][bl][0] = re; red[c][bl][1] = im;
  __syncthreads();

  const float cfrac = (16000.0f*dval(s))/343.0f; // fractional pts2rx_idx
  if (tid < 64){
    const int kk = grp*64 + tid;
    float rs = red[0][tid][0] + red[1][tid][0] + red[2][tid][0] + red[3][tid][0];
    float is = red[0][tid][1] + red[1][tid][1] + red[2][tid][1] + red[3][tid][1];
    float ang = -(TWO_PI_F/512.0f)*((float)kk*cfrac);
    float sp, cp; sincosf(ang, &sp, &cp);
    atomicAdd(&out[(b*NF + kk)*2],     rs*cp - is*sp);
    atomicAdd(&out[(b*NF + kk)*2 + 1], rs*sp + is*cp);
  } else if (grp == 0 && tid < 128){
    int t = tid - 64;
    float4 a = gs4[t], bq = gs4[t+64];
    float alt = (a.x - a.y + a.z - a.w) + (bq.x - bq.y + bq.z - bq.w);
    #pragma unroll
    for (int m=32; m>=1; m>>=1) alt += __shfl_xor(alt, m, 64);
    if (t == 0){
      float ang = -(TWO_PI_F/512.0f)*(256.0f*cfrac);
      float sp, cp; sincosf(ang, &sp, &cp);
      atomicAdd(&out[(b*NF + 256)*2],     alt*cp);
      atomicAdd(&out[(b*NF + 256)*2 + 1], alt*sp);
    }
  }
}

extern "C" void kernel_launch(void* const* d_in, const int* in_sizes, int n_in,
                              void* d_out, int out_size, void* d_ws, size_t ws_size,
                              hipStream_t stream)
{
  const float* rays_o      = (const float*)d_in[0];
  const float* position_tx = (const float*)d_in[1];
  const float* W1          = (const float*)d_in[2];
  const float* b1          = (const float*)d_in[3];
  const float* w_attn      = (const float*)d_in[4];
  const float* W_sig       = (const float*)d_in[5];
  const float* b_sig       = (const float*)d_in[6];
  float* out = (float*)d_out;

  // workspace layout (~9.2 MB total)
  char* ws = (char*)d_ws;
  __half* wh       = (__half*)ws;                               // 4*128*514*16*2B = 8,421,376
  float* w_arr     = (float*)(ws + 8421376);                    // 263,168
  int*   delay_arr = (int*)  (ws + 8421376 + 263168);           // 263,168
  float* g         = (float*)(ws + 8421376 + 2*263168);         // 262,144

  k1_rays  <<<BS*RAYS,      128, 0, stream>>>(rays_o, position_tx, W1, b1, w_attn,
                                              wh, w_arr, delay_arr, g, out);
  k2_bucket<<<BS*NS*SPLIT, 1024, 0, stream>>>(wh, w_arr, delay_arr, W_sig, b_sig, g);
  k3_dft   <<<BS*NS*4,      256, 0, stream>>>(g, out);
}